// Round 1
// baseline (609.951 us; speedup 1.0000x reference)
//
#include <hip/hip_runtime.h>
#include <hip/hip_bf16.h>

#define NN 50000
#define NE 800000
#define F 128
#define NCLS 16

// ws layout (4-byte units)
#define O_DEG      0          // int[50000]
#define O_CURSOR   50000      // int[50000]
#define O_COLSUM   100000     // float[128]
#define O_INVDEG   100128     // float[50000]
#define O_ROWSTART 150128     // int[50001]
#define O_BLOCKSUM 200144     // int[256]
#define O_SRCS     200400     // int[800000]
#define O_NEIGH    1000400    // float[50000*128]
#define O_H1       7400400    // float[50000*128]
#define O_H2       13800400   // float[50000*128]

#define SCAN_BLOCKS 196       // ceil(50000/256)

__global__ void hist_kernel(const int* __restrict__ dst, int* __restrict__ deg) {
    int e = blockIdx.x * 256 + threadIdx.x;
    if (e < NE) atomicAdd(&deg[dst[e]], 1);
}

__global__ void scan_partial(const int* __restrict__ deg, int* __restrict__ blocksum) {
    __shared__ int s[256];
    int i = blockIdx.x * 256 + threadIdx.x;
    s[threadIdx.x] = (i < NN) ? deg[i] : 0;
    __syncthreads();
    for (int off = 128; off > 0; off >>= 1) {
        if (threadIdx.x < off) s[threadIdx.x] += s[threadIdx.x + off];
        __syncthreads();
    }
    if (threadIdx.x == 0) blocksum[blockIdx.x] = s[0];
}

__global__ void scan_offsets(int* __restrict__ blocksum) {
    if (threadIdx.x == 0) {
        int off = 0;
        for (int i = 0; i < SCAN_BLOCKS; ++i) { int t = blocksum[i]; blocksum[i] = off; off += t; }
    }
}

__global__ void scan_final(const int* __restrict__ deg, const int* __restrict__ blocksum,
                           int* __restrict__ row_start, float* __restrict__ inv_deg) {
    __shared__ int s[256];
    int i = blockIdx.x * 256 + threadIdx.x;
    int v = (i < NN) ? deg[i] : 0;
    s[threadIdx.x] = v;
    __syncthreads();
    for (int off = 1; off < 256; off <<= 1) {
        int t = (threadIdx.x >= off) ? s[threadIdx.x - off] : 0;
        __syncthreads();
        s[threadIdx.x] += t;
        __syncthreads();
    }
    if (i < NN) {
        row_start[i] = blocksum[blockIdx.x] + s[threadIdx.x] - v;   // exclusive
        inv_deg[i] = 1.0f / (float)(v > 1 ? v : 1);
    }
    if (i == 0) row_start[NN] = NE;
}

__global__ void fill_csr(const int* __restrict__ src, const int* __restrict__ dst,
                         const int* __restrict__ row_start, int* __restrict__ cursor,
                         int* __restrict__ srcs) {
    int e = blockIdx.x * 256 + threadIdx.x;
    if (e >= NE) return;
    int d = dst[e];
    int pos = row_start[d] + atomicAdd(&cursor[d], 1);
    srcs[pos] = src[e];
}

// one block (128 threads) per node: pull-aggregate + scale by inv_deg
__global__ __launch_bounds__(128) void aggregate_kernel(
        const float* __restrict__ hin, const int* __restrict__ row_start,
        const int* __restrict__ srcs, const float* __restrict__ inv_deg,
        float* __restrict__ neigh) {
    int n = blockIdx.x;
    int f = threadIdx.x;
    int e0 = row_start[n], e1 = row_start[n + 1];
    float acc = 0.0f;
    for (int e = e0; e < e1; ++e) {
        int sNode = srcs[e];
        acc += hin[sNode * F + f];
    }
    neigh[n * F + f] = acc * inv_deg[n];
}

// hout = relu(hin@ws + neigh@wn + b); 64 rows per block, 256 threads, 8x4 per thread
__global__ __launch_bounds__(256) void gemm_relu(
        const float* __restrict__ hin, const float* __restrict__ neigh,
        const float* __restrict__ ws, const float* __restrict__ wn,
        const float* __restrict__ bias, float* __restrict__ hout) {
    __shared__ float a_s[F][64];   // transposed A tile: [k][row], 32 KB
    int tid = threadIdx.x;
    int tx = tid & 31, ty = tid >> 5;   // 32 col-groups x 8 row-groups
    int j0 = tx * 4, r0 = ty * 8;
    int row0 = blockIdx.x * 64;

    float acc[8][4];
    float4 b4 = *(const float4*)&bias[j0];
#pragma unroll
    for (int i = 0; i < 8; ++i) {
        acc[i][0] = b4.x; acc[i][1] = b4.y; acc[i][2] = b4.z; acc[i][3] = b4.w;
    }

#pragma unroll
    for (int m = 0; m < 2; ++m) {
        const float* __restrict__ A = m ? neigh : hin;
        const float* __restrict__ W = m ? wn : ws;
        if (m) __syncthreads();   // protect a_s reads from previous pass
        // stage A tile transposed: idx row-fastest -> conflict-free LDS writes
#pragma unroll
        for (int i = 0; i < 8; ++i) {
            int idx = tid + i * 256;
            int row = idx & 63, kq = idx >> 6;
            float4 v = make_float4(0.f, 0.f, 0.f, 0.f);
            int r = row0 + row;
            if (r < NN) v = *(const float4*)&A[r * F + kq * 4];
            a_s[kq * 4 + 0][row] = v.x;
            a_s[kq * 4 + 1][row] = v.y;
            a_s[kq * 4 + 2][row] = v.z;
            a_s[kq * 4 + 3][row] = v.w;
        }
        __syncthreads();
#pragma unroll 4
        for (int k = 0; k < F; ++k) {
            float4 w = *(const float4*)&W[k * F + j0];
            const float* ak = &a_s[k][0];
            float4 aLo = *(const float4*)(ak + r0);
            float4 aHi = *(const float4*)(ak + r0 + 4);
            float av[8] = {aLo.x, aLo.y, aLo.z, aLo.w, aHi.x, aHi.y, aHi.z, aHi.w};
            float wv[4] = {w.x, w.y, w.z, w.w};
#pragma unroll
            for (int i = 0; i < 8; ++i)
#pragma unroll
                for (int c = 0; c < 4; ++c)
                    acc[i][c] = fmaf(av[i], wv[c], acc[i][c]);
        }
    }

#pragma unroll
    for (int i = 0; i < 8; ++i) {
        int r = row0 + r0 + i;
        if (r < NN) {
            float4 o;
            o.x = fmaxf(acc[i][0], 0.f);
            o.y = fmaxf(acc[i][1], 0.f);
            o.z = fmaxf(acc[i][2], 0.f);
            o.w = fmaxf(acc[i][3], 0.f);
            *(float4*)&hout[r * F + j0] = o;
        }
    }
}

__global__ __launch_bounds__(256) void colsum_kernel(const float* __restrict__ h,
                                                     float* __restrict__ colsum) {
    int t = threadIdx.x;
    int c = t & 127, half = t >> 7;
    float acc = 0.f;
    for (int r = blockIdx.x * 2 + half; r < NN; r += gridDim.x * 2)
        acc += h[r * F + c];
    __shared__ float s[256];
    s[t] = acc;
    __syncthreads();
    if (t < 128) atomicAdd(&colsum[c], s[t] + s[t + 128]);
}

__global__ __launch_bounds__(128) void head_kernel(const float* __restrict__ colsum,
                                                   const float* __restrict__ w_head,
                                                   const float* __restrict__ b_head,
                                                   float* __restrict__ out) {
    __shared__ float pls[F];
    int t = threadIdx.x;
    float p = colsum[t] * (1.0f / (float)NN);
    pls[t] = p;
    out[NCLS + t] = p;   // pls part of output
    __syncthreads();
    if (t < NCLS) {
        float sc = b_head[t];
        for (int f = 0; f < F; ++f) sc += pls[f] * w_head[f * NCLS + t];
        out[t] = sc;     // score part of output
    }
}

extern "C" void kernel_launch(void* const* d_in, const int* in_sizes, int n_in,
                              void* d_out, int out_size, void* d_ws, size_t ws_size,
                              hipStream_t stream) {
    const float* x       = (const float*)d_in[0];
    const int*   src     = (const int*)d_in[1];
    const int*   dst     = (const int*)d_in[2];
    const float* w_self0 = (const float*)d_in[3];
    const float* w_neigh0= (const float*)d_in[4];
    const float* b0      = (const float*)d_in[5];
    const float* w_self1 = (const float*)d_in[6];
    const float* w_neigh1= (const float*)d_in[7];
    const float* b1      = (const float*)d_in[8];
    const float* w_self2 = (const float*)d_in[9];
    const float* w_neigh2= (const float*)d_in[10];
    const float* b2      = (const float*)d_in[11];
    const float* w_head  = (const float*)d_in[12];
    const float* b_head  = (const float*)d_in[13];
    float* out = (float*)d_out;

    int*   ws_i = (int*)d_ws;
    float* ws_f = (float*)d_ws;
    int*   deg      = ws_i + O_DEG;
    int*   cursor   = ws_i + O_CURSOR;
    float* colsum   = ws_f + O_COLSUM;
    float* inv_deg  = ws_f + O_INVDEG;
    int*   row_start= ws_i + O_ROWSTART;
    int*   blocksum = ws_i + O_BLOCKSUM;
    int*   srcs     = ws_i + O_SRCS;
    float* neigh    = ws_f + O_NEIGH;
    float* h1       = ws_f + O_H1;
    float* h2       = ws_f + O_H2;

    // zero deg + cursor + colsum (contiguous region)
    hipMemsetAsync(d_ws, 0, (size_t)(100128) * 4, stream);

    hist_kernel<<<3125, 256, 0, stream>>>(dst, deg);
    scan_partial<<<SCAN_BLOCKS, 256, 0, stream>>>(deg, blocksum);
    scan_offsets<<<1, 64, 0, stream>>>(blocksum);
    scan_final<<<SCAN_BLOCKS, 256, 0, stream>>>(deg, blocksum, row_start, inv_deg);
    fill_csr<<<3125, 256, 0, stream>>>(src, dst, row_start, cursor, srcs);

    const int GEMM_BLOCKS = (NN + 63) / 64;   // 782

    // layer 0: x -> h1
    aggregate_kernel<<<NN, 128, 0, stream>>>(x, row_start, srcs, inv_deg, neigh);
    gemm_relu<<<GEMM_BLOCKS, 256, 0, stream>>>(x, neigh, w_self0, w_neigh0, b0, h1);
    // layer 1: h1 -> h2
    aggregate_kernel<<<NN, 128, 0, stream>>>(h1, row_start, srcs, inv_deg, neigh);
    gemm_relu<<<GEMM_BLOCKS, 256, 0, stream>>>(h1, neigh, w_self1, w_neigh1, b1, h2);
    // layer 2: h2 -> h1
    aggregate_kernel<<<NN, 128, 0, stream>>>(h2, row_start, srcs, inv_deg, neigh);
    gemm_relu<<<GEMM_BLOCKS, 256, 0, stream>>>(h2, neigh, w_self2, w_neigh2, b2, h1);

    colsum_kernel<<<128, 256, 0, stream>>>(h1, colsum);
    head_kernel<<<1, 128, 0, stream>>>(colsum, w_head, b_head, out);
}

// Round 2
// 313.591 us; speedup vs baseline: 1.9450x; 1.9450x over previous
//
#include <hip/hip_runtime.h>
#include <hip/hip_bf16.h>
#include <stdint.h>

#define NN 50000
#define NE 800000
#define F 128
#define NCLS 16

typedef __attribute__((ext_vector_type(8))) short short8;
typedef __attribute__((ext_vector_type(4))) float f32x4;
typedef __attribute__((ext_vector_type(4))) unsigned int uint4v;

// ---- ws byte offsets ----
#define OB_DEG       0u          // int[50000]
#define OB_CURSOR    200000u     // int[50000]
#define OB_COLSUM    400000u     // float[128]
#define OB_INVDEG    400512u     // float[50000]
#define OB_ROWSTART  600512u     // int[50001]
#define OB_BLOCKSUM  800640u     // int[256]
#define OB_SRCS      801664u     // int[800000]
#define OB_WT        4001664u    // bf16 6*16384 (layout L)
#define OB_XB        4198400u    // bf16 [NN][128] layout L
#define OB_HB1       16998400u
#define OB_HB2       29798400u
#define OB_NB        42598400u   // ends 55398400

#define SCAN_BLOCKS 196

// ---- swizzled bf16 feature layout L ----
// element (row,k) at byte: row*256 + 16*(chunk(k) ^ (row&15)) + inchunk(k)
// chunk(k) = (k>>5)*4 | ((k>>2)&3); inchunk = ((k>>4)&1)*8 + (k&3)*2
__device__ __forceinline__ uint32_t swz_off(uint32_t row, uint32_t k) {
    uint32_t c = ((k >> 5) << 2) | ((k >> 2) & 3u);
    uint32_t b = (((k >> 4) & 1u) << 3) | ((k & 3u) << 1);
    return (row << 8) + (((c ^ (row & 15u)) << 4) | b);
}

// ================= CSR build (unchanged) =================
__global__ void hist_kernel(const int* __restrict__ dst, int* __restrict__ deg) {
    int e = blockIdx.x * 256 + threadIdx.x;
    if (e < NE) atomicAdd(&deg[dst[e]], 1);
}

__global__ void scan_partial(const int* __restrict__ deg, int* __restrict__ blocksum) {
    __shared__ int s[256];
    int i = blockIdx.x * 256 + threadIdx.x;
    s[threadIdx.x] = (i < NN) ? deg[i] : 0;
    __syncthreads();
    for (int off = 128; off > 0; off >>= 1) {
        if (threadIdx.x < off) s[threadIdx.x] += s[threadIdx.x + off];
        __syncthreads();
    }
    if (threadIdx.x == 0) blocksum[blockIdx.x] = s[0];
}

__global__ void scan_offsets(int* __restrict__ blocksum) {
    if (threadIdx.x == 0) {
        int off = 0;
        for (int i = 0; i < SCAN_BLOCKS; ++i) { int t = blocksum[i]; blocksum[i] = off; off += t; }
    }
}

__global__ void scan_final(const int* __restrict__ deg, const int* __restrict__ blocksum,
                           int* __restrict__ row_start, float* __restrict__ inv_deg) {
    __shared__ int s[256];
    int i = blockIdx.x * 256 + threadIdx.x;
    int v = (i < NN) ? deg[i] : 0;
    s[threadIdx.x] = v;
    __syncthreads();
    for (int off = 1; off < 256; off <<= 1) {
        int t = (threadIdx.x >= off) ? s[threadIdx.x - off] : 0;
        __syncthreads();
        s[threadIdx.x] += t;
        __syncthreads();
    }
    if (i < NN) {
        row_start[i] = blocksum[blockIdx.x] + s[threadIdx.x] - v;
        inv_deg[i] = 1.0f / (float)(v > 1 ? v : 1);
    }
    if (i == 0) row_start[NN] = NE;
}

__global__ void fill_csr(const int* __restrict__ src, const int* __restrict__ dst,
                         const int* __restrict__ row_start, int* __restrict__ cursor,
                         int* __restrict__ srcs) {
    int e = blockIdx.x * 256 + threadIdx.x;
    if (e >= NE) return;
    int d = dst[e];
    int pos = row_start[d] + atomicAdd(&cursor[d], 1);
    srcs[pos] = src[e];
}

// ================= conversions =================
__global__ __launch_bounds__(256) void convert_x(const float* __restrict__ x,
                                                 uint8_t* __restrict__ xb) {
    int t = blockIdx.x * 256 + threadIdx.x;          // NN*64 pair-slots
    int row = t >> 6;
    int k0 = (t & 63) << 1;
    float2 v = *(const float2*)(x + row * F + k0);
    __hip_bfloat16 l = __float2bfloat16(v.x), h = __float2bfloat16(v.y);
    uint32_t pk = ((uint32_t)(*(uint16_t*)&h) << 16) | (uint32_t)(*(uint16_t*)&l);
    *(uint32_t*)(xb + swz_off((uint32_t)row, (uint32_t)k0)) = pk;
}

// transpose + convert weights: Wt[n][k] = W[k][n], layout L on (n,k)
__global__ __launch_bounds__(256) void prep_w(const float* __restrict__ w0, const float* __restrict__ w1,
                                              const float* __restrict__ w2, const float* __restrict__ w3,
                                              const float* __restrict__ w4, const float* __restrict__ w5,
                                              uint8_t* __restrict__ wt) {
    int m = blockIdx.y;
    const float* w = m == 0 ? w0 : m == 1 ? w1 : m == 2 ? w2 : m == 3 ? w3 : m == 4 ? w4 : w5;
    int t = blockIdx.x * 256 + threadIdx.x;          // 8192 pair-slots
    int n = t >> 6;
    int k0 = (t & 63) << 1;
    float lo = w[k0 * F + n];
    float hi = w[(k0 + 1) * F + n];
    __hip_bfloat16 l = __float2bfloat16(lo), h = __float2bfloat16(hi);
    uint32_t pk = ((uint32_t)(*(uint16_t*)&h) << 16) | (uint32_t)(*(uint16_t*)&l);
    *(uint32_t*)(wt + (uint32_t)m * 32768u + swz_off((uint32_t)n, (uint32_t)k0)) = pk;
}

// ================= aggregate: one wave per node, bf16 gather =================
__global__ __launch_bounds__(256) void aggregate_b(
        const uint8_t* __restrict__ hb, const int* __restrict__ row_start,
        const int* __restrict__ srcs, const float* __restrict__ inv_deg,
        uint8_t* __restrict__ nb) {
    int wid = blockIdx.x * 4 + (threadIdx.x >> 6);
    int lane = threadIdx.x & 63;
    int k0 = lane << 1;
    uint32_t c = ((uint32_t)(k0 >> 5) << 2) | (((uint32_t)k0 >> 2) & 3u);
    uint32_t b = ((((uint32_t)k0 >> 4) & 1u) << 3) | (((uint32_t)k0 & 3u) << 1);
    int e0 = row_start[wid], e1 = row_start[wid + 1];
    float a0 = 0.f, a1 = 0.f;
    int e = e0;
    for (; e + 4 <= e1; e += 4) {
        int s0 = srcs[e], s1 = srcs[e + 1], s2 = srcs[e + 2], s3 = srcs[e + 3];
        uint32_t d0 = *(const uint32_t*)(hb + ((uint32_t)s0 << 8) + (((c ^ ((uint32_t)s0 & 15u)) << 4) | b));
        uint32_t d1 = *(const uint32_t*)(hb + ((uint32_t)s1 << 8) + (((c ^ ((uint32_t)s1 & 15u)) << 4) | b));
        uint32_t d2 = *(const uint32_t*)(hb + ((uint32_t)s2 << 8) + (((c ^ ((uint32_t)s2 & 15u)) << 4) | b));
        uint32_t d3 = *(const uint32_t*)(hb + ((uint32_t)s3 << 8) + (((c ^ ((uint32_t)s3 & 15u)) << 4) | b));
        a0 += __uint_as_float(d0 << 16) + __uint_as_float(d1 << 16)
            + __uint_as_float(d2 << 16) + __uint_as_float(d3 << 16);
        a1 += __uint_as_float(d0 & 0xffff0000u) + __uint_as_float(d1 & 0xffff0000u)
            + __uint_as_float(d2 & 0xffff0000u) + __uint_as_float(d3 & 0xffff0000u);
    }
    for (; e < e1; ++e) {
        int s0 = srcs[e];
        uint32_t d0 = *(const uint32_t*)(hb + ((uint32_t)s0 << 8) + (((c ^ ((uint32_t)s0 & 15u)) << 4) | b));
        a0 += __uint_as_float(d0 << 16);
        a1 += __uint_as_float(d0 & 0xffff0000u);
    }
    float idg = inv_deg[wid];
    a0 *= idg; a1 *= idg;
    __hip_bfloat16 l = __float2bfloat16(a0), h = __float2bfloat16(a1);
    uint32_t pk = ((uint32_t)(*(uint16_t*)&h) << 16) | (uint32_t)(*(uint16_t*)&l);
    *(uint32_t*)(nb + ((uint32_t)wid << 8) + (((c ^ ((uint32_t)wid & 15u)) << 4) | b)) = pk;
}

// ================= MFMA GEMM: hout = relu(As@Ws + An@Wn + b), all layout L ====
__global__ __launch_bounds__(256) void gemm_mfma(
        const uint8_t* __restrict__ a_self, const uint8_t* __restrict__ a_neigh,
        const uint8_t* __restrict__ wt_self, const uint8_t* __restrict__ wt_neigh,
        const float* __restrict__ bias, uint8_t* __restrict__ hout) {
    __shared__ uint4v As4[1024];   // 16 KB: 64 rows x 256 B (layout L)
    __shared__ uint4v Ws4[2048];   // 32 KB: 128 n-rows x 256 B (layout L)
    int tid = threadIdx.x;
    int lane = tid & 63, wave = tid >> 6;
    int rl = lane & 15, g = lane >> 4;
    int row0 = blockIdx.x * 64;

    f32x4 acc[8];
    f32x4 z = {0.f, 0.f, 0.f, 0.f};
#pragma unroll
    for (int nt = 0; nt < 8; ++nt) acc[nt] = z;

    const char* AsB = (const char*)As4;
    const char* WsB = (const char*)Ws4;

#pragma unroll
    for (int pass = 0; pass < 2; ++pass) {
        if (pass) __syncthreads();
        const uint4v* ga = (const uint4v*)((pass ? a_neigh : a_self) + (size_t)row0 * 256);
        const uint4v* gw = (const uint4v*)(pass ? wt_neigh : wt_self);
#pragma unroll
        for (int i = 0; i < 4; ++i) As4[tid + i * 256] = ga[tid + i * 256];
#pragma unroll
        for (int i = 0; i < 8; ++i) Ws4[tid + i * 256] = gw[tid + i * 256];
        __syncthreads();
#pragma unroll
        for (int ks = 0; ks < 4; ++ks) {
            int chunk = ((ks << 2) | g) ^ rl;
            short8 a = *(const short8*)(AsB + ((wave * 16 + rl) << 8) + (chunk << 4));
#pragma unroll
            for (int nt = 0; nt < 8; ++nt) {
                short8 bb = *(const short8*)(WsB + ((nt * 16 + rl) << 8) + (chunk << 4));
                acc[nt] = __builtin_amdgcn_mfma_f32_16x16x32_bf16(a, bb, acc[nt], 0, 0, 0);
            }
        }
    }

#pragma unroll
    for (int nt = 0; nt < 8; ++nt) {
        int col = nt * 16 + rl;
        float bv = bias[col];
#pragma unroll
        for (int i = 0; i < 4; ++i) {
            int row = row0 + wave * 16 + g * 4 + i;
            if (row < NN) {
                float v = fmaxf(acc[nt][i] + bv, 0.f);
                __hip_bfloat16 hv = __float2bfloat16(v);
                *(__hip_bfloat16*)(hout + swz_off((uint32_t)row, (uint32_t)col)) = hv;
            }
        }
    }
}

// ================= column sum over bf16 layout L =================
__global__ __launch_bounds__(256) void colsum_b(const uint8_t* __restrict__ hb,
                                                float* __restrict__ colsum) {
    int wave = threadIdx.x >> 6, lane = threadIdx.x & 63;
    int k0 = lane << 1;
    uint32_t c = ((uint32_t)(k0 >> 5) << 2) | (((uint32_t)k0 >> 2) & 3u);
    uint32_t b = ((((uint32_t)k0 >> 4) & 1u) << 3) | (((uint32_t)k0 & 3u) << 1);
    float a0 = 0.f, a1 = 0.f;
    for (int r = blockIdx.x * 4 + wave; r < NN; r += gridDim.x * 4) {
        uint32_t d = *(const uint32_t*)(hb + ((uint32_t)r << 8) + (((c ^ ((uint32_t)r & 15u)) << 4) | b));
        a0 += __uint_as_float(d << 16);
        a1 += __uint_as_float(d & 0xffff0000u);
    }
    __shared__ float s[4][128];
    s[wave][k0] = a0; s[wave][k0 + 1] = a1;
    __syncthreads();
    if (wave == 0) {
        float v0 = s[0][k0] + s[1][k0] + s[2][k0] + s[3][k0];
        float v1 = s[0][k0 + 1] + s[1][k0 + 1] + s[2][k0 + 1] + s[3][k0 + 1];
        atomicAdd(&colsum[k0], v0);
        atomicAdd(&colsum[k0 + 1], v1);
    }
}

__global__ __launch_bounds__(128) void head_kernel(const float* __restrict__ colsum,
                                                   const float* __restrict__ w_head,
                                                   const float* __restrict__ b_head,
                                                   float* __restrict__ out) {
    __shared__ float pls[F];
    int t = threadIdx.x;
    float p = colsum[t] * (1.0f / (float)NN);
    pls[t] = p;
    out[NCLS + t] = p;
    __syncthreads();
    if (t < NCLS) {
        float sc = b_head[t];
        for (int f = 0; f < F; ++f) sc += pls[f] * w_head[f * NCLS + t];
        out[t] = sc;
    }
}

extern "C" void kernel_launch(void* const* d_in, const int* in_sizes, int n_in,
                              void* d_out, int out_size, void* d_ws, size_t ws_size,
                              hipStream_t stream) {
    const float* x       = (const float*)d_in[0];
    const int*   src     = (const int*)d_in[1];
    const int*   dst     = (const int*)d_in[2];
    const float* w_self0 = (const float*)d_in[3];
    const float* w_neigh0= (const float*)d_in[4];
    const float* b0      = (const float*)d_in[5];
    const float* w_self1 = (const float*)d_in[6];
    const float* w_neigh1= (const float*)d_in[7];
    const float* b1      = (const float*)d_in[8];
    const float* w_self2 = (const float*)d_in[9];
    const float* w_neigh2= (const float*)d_in[10];
    const float* b2      = (const float*)d_in[11];
    const float* w_head  = (const float*)d_in[12];
    const float* b_head  = (const float*)d_in[13];
    float* out = (float*)d_out;

    uint8_t* ws = (uint8_t*)d_ws;
    int*   deg      = (int*)(ws + OB_DEG);
    int*   cursor   = (int*)(ws + OB_CURSOR);
    float* colsum   = (float*)(ws + OB_COLSUM);
    float* inv_deg  = (float*)(ws + OB_INVDEG);
    int*   row_start= (int*)(ws + OB_ROWSTART);
    int*   blocksum = (int*)(ws + OB_BLOCKSUM);
    int*   srcs     = (int*)(ws + OB_SRCS);
    uint8_t* wt     = ws + OB_WT;
    uint8_t* xb     = ws + OB_XB;
    uint8_t* hb1    = ws + OB_HB1;
    uint8_t* hb2    = ws + OB_HB2;
    uint8_t* nb     = ws + OB_NB;

    // zero deg + cursor + colsum (contiguous at start)
    hipMemsetAsync(d_ws, 0, 400512, stream);

    convert_x<<<12500, 256, 0, stream>>>(x, xb);
    prep_w<<<dim3(32, 6), 256, 0, stream>>>(w_self0, w_neigh0, w_self1, w_neigh1,
                                            w_self2, w_neigh2, wt);

    hist_kernel<<<3125, 256, 0, stream>>>(dst, deg);
    scan_partial<<<SCAN_BLOCKS, 256, 0, stream>>>(deg, blocksum);
    scan_offsets<<<1, 64, 0, stream>>>(blocksum);
    scan_final<<<SCAN_BLOCKS, 256, 0, stream>>>(deg, blocksum, row_start, inv_deg);
    fill_csr<<<3125, 256, 0, stream>>>(src, dst, row_start, cursor, srcs);

    const int GB = (NN + 63) / 64;   // 782

    // layer 0
    aggregate_b<<<12500, 256, 0, stream>>>(xb, row_start, srcs, inv_deg, nb);
    gemm_mfma<<<GB, 256, 0, stream>>>(xb, nb, wt + 0 * 32768, wt + 1 * 32768, b0, hb1);
    // layer 1
    aggregate_b<<<12500, 256, 0, stream>>>(hb1, row_start, srcs, inv_deg, nb);
    gemm_mfma<<<GB, 256, 0, stream>>>(hb1, nb, wt + 2 * 32768, wt + 3 * 32768, b1, hb2);
    // layer 2
    aggregate_b<<<12500, 256, 0, stream>>>(hb2, row_start, srcs, inv_deg, nb);
    gemm_mfma<<<GB, 256, 0, stream>>>(hb2, nb, wt + 4 * 32768, wt + 5 * 32768, b2, hb1);

    colsum_b<<<256, 256, 0, stream>>>(hb1, colsum);
    head_kernel<<<1, 128, 0, stream>>>(colsum, w_head, b_head, out);
}